// Round 1
// baseline (340.426 us; speedup 1.0000x reference)
//
#include <hip/hip_runtime.h>
#include <hip/hip_bf16.h>

// f32-uniform output buffer: final_out [B,512] (bf16-rounded f32),
// guide_loss f32 @ B*512, sel_emb [B,128] f32 @ B*512+1.
// B=16384, E=8, D_IN=900, D_MODEL=512, D_SEL=128, top-2.

#define B_ROWS 16384
#define DIN 900
#define DM 512
#define DSEL 128
#define KP 928
#define NKS 29
#define MAXT 192
#define EPSF 1e-9f

#define OUT_GUIDE (B_ROWS*DM)
#define OUT_SEL   (B_ROWS*DM + 1)

// workspace layout (bytes); total ~8.4 MB
#define WS_COUNTS 0                      // int[64]
#define WS_PART   512                    // float[64]
#define WS_NT     768                    // int
#define WS_OFF    1024                   // int[64]
#define WS_ENT    2048                   // int4[448]
#define WS_BB     9216                   // int[64*64] block bases
#define WS_PIDLR  25600                  // int[B]  pid | (lrank<<8)
#define WS_GATEB  91136                  // float2[B]
#define WS_W8     222208                 // float[B*8] inactive-mixture weights
#define WS_ROWSS  746496                 // int[B]
#define WS_WT     812032                 // ushort[E*DM*KP] (7.6 MB)

typedef __attribute__((ext_vector_type(8))) short short8;
typedef __attribute__((ext_vector_type(8))) unsigned short ushort8;
typedef __attribute__((ext_vector_type(4))) float floatx4;

__device__ inline unsigned short f2bf(float v){
  union { __hip_bfloat16 h; unsigned short u; } c;
  c.h = __float2bfloat16(v);
  return c.u;
}
__device__ inline float bf2f(unsigned short u){
  union { unsigned int i; float f; } c;
  c.i = ((unsigned int)u) << 16;
  return c.f;
}

// ---- W f32 [E,900,512] -> bf16 transposed [E,512,928] (K zero-padded) ----
__global__ __launch_bounds__(256) void cvtw_k(const float* __restrict__ W,
                                              unsigned short* __restrict__ wt){
  __shared__ unsigned short tl[64][65];
  int kt = blockIdx.x, ntb = blockIdx.y, e = blockIdx.z;
  int c = threadIdx.x & 63, q = threadIdx.x >> 6;
  for (int i = 0; i < 16; i++){
    int kl = q + i*4;
    int k = kt*64 + kl;
    float v = (k < DIN) ? W[((size_t)e*DIN + k)*DM + ntb*64 + c] : 0.f;
    tl[kl][c] = f2bf(v);
  }
  __syncthreads();
  for (int i = 0; i < 16; i++){
    int nl = q + i*4;
    int k = kt*64 + c;
    if (k < KP)
      wt[((size_t)e*DM + ntb*64 + nl)*KP + k] = tl[c][nl];
  }
}

// ---- gating: thread-per-row; no hot atomics ----
__global__ __launch_bounds__(256) void gating_k(const float* __restrict__ logits,
                                                const int* __restrict__ masks,
                                                int* __restrict__ counts,
                                                float* __restrict__ partials,
                                                int* __restrict__ pidlr,
                                                float2* __restrict__ gatesb,
                                                float* __restrict__ w8,
                                                int* __restrict__ blockbase){
  __shared__ int hist[64];
  __shared__ float wsum[4];
  int t = threadIdx.x;
  if (t < 64) hist[t] = 0;
  __syncthreads();
  int b = blockIdx.x*256 + t;
  float4 l0 = *(const float4*)&logits[(size_t)b*8];
  float4 l1 = *(const float4*)&logits[(size_t)b*8 + 4];
  int4  m0 = *(const int4*)&masks[(size_t)b*8];
  int4  m1 = *(const int4*)&masks[(size_t)b*8 + 4];
  float raw[8] = {l0.x,l0.y,l0.z,l0.w,l1.x,l1.y,l1.z,l1.w};
  int   mk[8]  = {m0.x,m0.y,m0.z,m0.w,m1.x,m1.y,m1.z,m1.w};
  float mx = raw[0];
  for (int e = 1; e < 8; e++) mx = fmaxf(mx, raw[e]);
  float Z = 0.f;
  for (int e = 0; e < 8; e++){ raw[e] = expf(raw[e]-mx); Z += raw[e]; }
  float invZ = 1.f/Z;
  float act[8], ina[8]; float srm = 0.f, isum = 0.f;
  for (int e = 0; e < 8; e++){
    raw[e] *= invZ;
    if (mk[e] == 1){ act[e] = raw[e]; ina[e] = 0.f; srm += raw[e]; }
    else           { act[e] = 0.f;    ina[e] = raw[e]; isum += raw[e]; }
  }
  float v1 = -1.f, v2 = -1.f; int e1 = 0, e2 = 0;
  for (int e = 0; e < 8; e++){
    float a = act[e];
    if (a > v1){ v2 = v1; e2 = e1; v1 = a; e1 = e; }
    else if (a > v2){ v2 = a; e2 = e; }
  }
  float den = v1 + v2 + EPSF;
  float g1 = v1/den, g2 = v2/den;
  int lo, hi; float gl, gh;
  if (e1 < e2){ lo = e1; hi = e2; gl = g1; gh = g2; }
  else        { lo = e2; hi = e1; gl = g2; gh = g1; }
  int pid = lo*8 + hi;
  float invI = 1.f/(isum + EPSF);
  for (int e = 0; e < 8; e++) w8[(size_t)b*8 + e] = ina[e]*invI;
  gatesb[b] = make_float2(gl, gh);
  int lr = atomicAdd(&hist[pid], 1);     // LDS atomic: local rank
  pidlr[b] = pid | (lr << 8);
  // block reduce srm -> partials[blockIdx]
  float s = srm;
  for (int sft = 32; sft > 0; sft >>= 1) s += __shfl_down(s, sft, 64);
  if ((t & 63) == 0) wsum[t >> 6] = s;
  __syncthreads();
  if (t < 64){
    int c = hist[t];
    int base = 0;
    if (c > 0) base = atomicAdd(&counts[t], c);   // <=64 atomics/block
    blockbase[blockIdx.x*64 + t] = base;
  }
  if (t == 0) partials[blockIdx.x] = wsum[0] + wsum[1] + wsum[2] + wsum[3];
}

// ---- selection embedding (+ fused scatter): coalesced, 2 rows per block ----
__global__ __launch_bounds__(256) void selemb_k(const float* __restrict__ sel,
                                                const float* __restrict__ w8,
                                                const int* __restrict__ pidlr,
                                                const int* __restrict__ off,
                                                const int* __restrict__ blockbase,
                                                int* __restrict__ rows_s,
                                                float* __restrict__ out){
  int t = threadIdx.x;
  int b = blockIdx.x*2 + (t >> 7);
  int d = t & 127;
  if (d == 0){
    int pl = pidlr[b];
    int p = pl & 63;
    int lr = pl >> 8;
    rows_s[off[p] + blockbase[(b >> 8)*64 + p] + lr] = b;
  }
  const float* wr = w8 + (size_t)b*8;
  const float* sb = sel + (size_t)b*(8*DSEL);
  float a = 0.f;
  for (int e = 0; e < 8; e++) a += wr[e] * sb[e*DSEL + d];
  out[OUT_SEL + (size_t)b*DSEL + d] = a;
}

// ---- worklist: one 64-lane wave; shuffle scans; guide loss ----
__global__ void worklist_k(const int* __restrict__ counts,
                           const float* __restrict__ partials,
                           int* __restrict__ off, int* __restrict__ ntp,
                           int4* __restrict__ entries,
                           float* __restrict__ out){
  int lane = threadIdx.x;      // 64 threads
  int c = counts[lane];
  int sc = c;
  for (int s = 1; s < 64; s <<= 1){ int v = __shfl_up(sc, s, 64); if (lane >= s) sc += v; }
  int offp = sc - c;
  off[lane] = offp;
  int nt = (c + 127) >> 7;
  int snt = nt;
  for (int s = 1; s < 64; s <<= 1){ int v = __shfl_up(snt, s, 64); if (lane >= s) snt += v; }
  int tbase = snt - nt;
  int elo = lane >> 3, ehi = lane & 7;
  for (int j = 0; j < nt; ++j){
    int nr = c - j*128; if (nr > 128) nr = 128;
    entries[tbase + j] = make_int4(elo, ehi, offp + j*128, nr);
  }
  int tot = __shfl(snt, 63, 64);
  if (lane == 0) *ntp = tot;
  float p = partials[lane];
  for (int s = 32; s > 0; s >>= 1) p += __shfl_down(p, s, 64);
  if (lane == 0){
    float sv = p * (1.f/B_ROWS);
    float d = 1.f - sv;
    out[OUT_GUIDE] = d*d;
  }
}

// ---- grouped GEMM: single unscaled bf16 x staging, BOTH experts per K-step,
//      double-buffered LDS (1 barrier/K-step), reg-prefetch of next chunk ----
__global__ __launch_bounds__(256, 2) void gemm_k(const float* __restrict__ xf,
                                              const unsigned short* __restrict__ wt,
                                              const float* __restrict__ bias,
                                              const int* __restrict__ ntp,
                                              const int4* __restrict__ entries,
                                              const int* __restrict__ rows_s,
                                              const float2* __restrict__ gatesb,
                                              float* __restrict__ out){
  int tile = blockIdx.x;
  if (tile >= *ntp) return;
  int4 ent = entries[tile];
  int elo = ent.x, ehi = ent.y, start = ent.z, nrows = ent.w;

  __shared__ __align__(16) unsigned short xs[2][128*40];
  __shared__ int   gidx_s[128];
  __shared__ float glo_s[128];
  __shared__ float ghi_s[128];

  int t = threadIdx.x;
  if (t < 128){
    if (t < nrows){
      int g = rows_s[start + t];
      gidx_s[t] = g;
      float2 gg = gatesb[g];
      glo_s[t] = gg.x; ghi_s[t] = gg.y;
    } else { gidx_s[t] = -1; glo_s[t] = 0.f; ghi_s[t] = 0.f; }
  }
  __syncthreads();

  int lane = t & 63, wid = t >> 6;
  int wrow = wid >> 1, wcol = wid & 1;
  int quad = lane >> 4, l16 = lane & 15;
  int colbase = blockIdx.y*128 + wcol*64;

  int srow = t >> 1, skc = t & 1;
  int sg = gidx_s[srow];
  const float* xrow = xf + (size_t)(sg >= 0 ? sg : 0)*DIN + skc*16;

  const unsigned short* wb0 = wt + (size_t)elo*DM*KP;
  const unsigned short* wb1 = wt + (size_t)ehi*DM*KP;

  floatx4 acc[2][4][4];
  for (int i = 0; i < 2; i++) for (int j = 0; j < 4; j++) for (int k = 0; k < 4; k++)
    for (int r = 0; r < 4; r++) acc[i][j][k][r] = 0.f;

  // prologue: load + convert + write chunk 0 into buffer 0 (ks=0 < 28, full path)
  {
    const float4* p = (const float4*)(xrow);
    float4 a0 = p[0], a1 = p[1], a2 = p[2], a3 = p[3];
    ushort8 y0, y1;
    y0[0]=f2bf(a0.x); y0[1]=f2bf(a0.y); y0[2]=f2bf(a0.z); y0[3]=f2bf(a0.w);
    y0[4]=f2bf(a1.x); y0[5]=f2bf(a1.y); y0[6]=f2bf(a1.z); y0[7]=f2bf(a1.w);
    y1[0]=f2bf(a2.x); y1[1]=f2bf(a2.y); y1[2]=f2bf(a2.z); y1[3]=f2bf(a2.w);
    y1[4]=f2bf(a3.x); y1[5]=f2bf(a3.y); y1[6]=f2bf(a3.z); y1[7]=f2bf(a3.w);
    *((ushort8*)&xs[0][srow*40 + skc*16])     = y0;
    *((ushort8*)&xs[0][srow*40 + skc*16 + 8]) = y1;
  }

  for (int ks = 0; ks < NKS; ++ks){
    __syncthreads();                 // buffer ks&1 ready; prior reads of other buffer done
    int cur = ks & 1;
    int nks = ks + 1;

    // issue next chunk's global loads now — they fly under the MFMAs below
    float4 b0, b1, b2, b3;
    if (nks < NKS){
      if (nks < 28){
        const float4* p = (const float4*)(xrow + nks*32);
        b0 = p[0]; b1 = p[1]; b2 = p[2]; b3 = p[3];
      } else {
        float tmp[16];
        for (int j = 0; j < 16; j++){
          int k = nks*32 + skc*16 + j;
          tmp[j] = (k < DIN) ? xrow[nks*32 + j] : 0.f;
        }
        b0 = make_float4(tmp[0],tmp[1],tmp[2],tmp[3]);
        b1 = make_float4(tmp[4],tmp[5],tmp[6],tmp[7]);
        b2 = make_float4(tmp[8],tmp[9],tmp[10],tmp[11]);
        b3 = make_float4(tmp[12],tmp[13],tmp[14],tmp[15]);
      }
    }

    // A fragments: shared by both experts
    short8 af[4];
    for (int mt = 0; mt < 4; ++mt)
      af[mt] = *((const short8*)&xs[cur][(wrow*64 + mt*16 + l16)*40 + quad*8]);

    // 32 MFMAs per wave per barrier: both experts from one staged tile
    for (int nt = 0; nt < 4; ++nt){
      int n = colbase + nt*16 + l16;
      short8 bf0 = *((const short8*)(wb0 + (size_t)n*KP + ks*32 + quad*8));
      short8 bf1 = *((const short8*)(wb1 + (size_t)n*KP + ks*32 + quad*8));
      for (int mt = 0; mt < 4; ++mt)
        acc[0][mt][nt] = __builtin_amdgcn_mfma_f32_16x16x32_bf16(af[mt], bf0, acc[0][mt][nt], 0, 0, 0);
      for (int mt = 0; mt < 4; ++mt)
        acc[1][mt][nt] = __builtin_amdgcn_mfma_f32_16x16x32_bf16(af[mt], bf1, acc[1][mt][nt], 0, 0, 0);
    }

    // convert + write next chunk into the other buffer (before next barrier)
    if (nks < NKS){
      ushort8 y0, y1;
      y0[0]=f2bf(b0.x); y0[1]=f2bf(b0.y); y0[2]=f2bf(b0.z); y0[3]=f2bf(b0.w);
      y0[4]=f2bf(b1.x); y0[5]=f2bf(b1.y); y0[6]=f2bf(b1.z); y0[7]=f2bf(b1.w);
      y1[0]=f2bf(b2.x); y1[1]=f2bf(b2.y); y1[2]=f2bf(b2.z); y1[3]=f2bf(b2.w);
      y1[4]=f2bf(b3.x); y1[5]=f2bf(b3.y); y1[6]=f2bf(b3.z); y1[7]=f2bf(b3.w);
      *((ushort8*)&xs[cur^1][srow*40 + skc*16])     = y0;
      *((ushort8*)&xs[cur^1][srow*40 + skc*16 + 8]) = y1;
    }
  }

  // epilogue: gates + bias applied in f32 here (numerically == ref's g*(xW+b))
  for (int nt = 0; nt < 4; ++nt){
    int n = colbase + nt*16 + l16;
    float blo = bias[elo*DM + n];
    float bhi = bias[ehi*DM + n];
    for (int mt = 0; mt < 4; ++mt){
      int rl = wrow*64 + mt*16 + quad*4;
      for (int r = 0; r < 4; ++r){
        int rr = rl + r;
        int grow = gidx_s[rr];
        if (grow >= 0){
          float v = glo_s[rr]*(acc[0][mt][nt][r] + blo) + ghi_s[rr]*(acc[1][mt][nt][r] + bhi);
          out[(size_t)grow*DM + n] = bf2f(f2bf(v));
        }
      }
    }
  }
}

extern "C" void kernel_launch(void* const* d_in, const int* in_sizes, int n_in,
                              void* d_out, int out_size, void* d_ws, size_t ws_size,
                              hipStream_t stream){
  const float* x      = (const float*)d_in[0];
  const float* logits = (const float*)d_in[1];
  const int*   masks  = (const int*)d_in[2];
  const float* sel    = (const float*)d_in[3];
  const float* W      = (const float*)d_in[4];
  const float* bias   = (const float*)d_in[5];
  float* out = (float*)d_out;
  char* ws = (char*)d_ws;
  int*    counts   = (int*)(ws + WS_COUNTS);
  float*  partials = (float*)(ws + WS_PART);
  int*    ntp      = (int*)(ws + WS_NT);
  int*    off      = (int*)(ws + WS_OFF);
  int4*   entries  = (int4*)(ws + WS_ENT);
  int*    blockbase= (int*)(ws + WS_BB);
  int*    pidlr    = (int*)(ws + WS_PIDLR);
  float2* gatesb   = (float2*)(ws + WS_GATEB);
  float*  w8       = (float*)(ws + WS_W8);
  int*    rows_s   = (int*)(ws + WS_ROWSS);
  unsigned short* wt = (unsigned short*)(ws + WS_WT);

  hipMemsetAsync(ws, 0, 256, stream);   // counts
  cvtw_k<<<dim3(15, 8, 8), 256, 0, stream>>>(W, wt);
  gating_k<<<B_ROWS/256, 256, 0, stream>>>(logits, masks, counts, partials, pidlr, gatesb, w8, blockbase);
  worklist_k<<<1, 64, 0, stream>>>(counts, partials, off, ntp, entries, out);
  selemb_k<<<B_ROWS/2, 256, 0, stream>>>(sel, w8, pidlr, off, blockbase, rows_s, out);
  gemm_k<<<dim3(MAXT, 4), 256, 0, stream>>>(x, wt, bias, ntp, entries, rows_s, gatesb, out);
}

// Round 3
// 332.627 us; speedup vs baseline: 1.0234x; 1.0234x over previous
//
#include <hip/hip_runtime.h>
#include <hip/hip_bf16.h>

// f32-uniform output buffer: final_out [B,512] (bf16-rounded f32),
// guide_loss f32 @ B*512, sel_emb [B,128] f32 @ B*512+1.
// B=16384, E=8, D_IN=900, D_MODEL=512, D_SEL=128, top-2.

#define B_ROWS 16384
#define DIN 900
#define DM 512
#define DSEL 128
#define KP 928
#define NKS 29
#define MAXT 192
#define EPSF 1e-9f

#define OUT_GUIDE (B_ROWS*DM)
#define OUT_SEL   (B_ROWS*DM + 1)

// workspace layout (bytes); total ~8.4 MB (proven footprint)
#define WS_COUNTS 0                      // int[64]
#define WS_PART   512                    // float[64]
#define WS_NT     768                    // int
#define WS_OFF    1024                   // int[64]
#define WS_ENT    2048                   // int4[448]
#define WS_BB     9216                   // int[64*64] block bases
#define WS_PIDLR  25600                  // int[B]  pid | (lrank<<8)
#define WS_GATEB  91136                  // float2[B]
#define WS_W8     222208                 // float[B*8] inactive-mixture weights
#define WS_ROWSS  746496                 // int[B]
#define WS_WT     812032                 // ushort[E*32*29*512] frag-tiled W (7.6 MB)

#define FRSTRIDE 14848                   // 29*512: wt2 stride between col-groups

typedef __attribute__((ext_vector_type(8))) short short8;
typedef __attribute__((ext_vector_type(8))) unsigned short ushort8;
typedef __attribute__((ext_vector_type(4))) float floatx4;

__device__ inline unsigned short f2bf(float v){
  union { __hip_bfloat16 h; unsigned short u; } c;
  c.h = __float2bfloat16(v);
  return c.u;
}
__device__ inline float bf2f(unsigned short u){
  union { unsigned int i; float f; } c;
  c.i = ((unsigned int)u) << 16;
  return c.f;
}
__device__ inline short8 pack8(float4 a, float4 b){
  union { ushort8 u; short8 s; } c;
  c.u[0]=f2bf(a.x); c.u[1]=f2bf(a.y); c.u[2]=f2bf(a.z); c.u[3]=f2bf(a.w);
  c.u[4]=f2bf(b.x); c.u[5]=f2bf(b.y); c.u[6]=f2bf(b.z); c.u[7]=f2bf(b.w);
  return c.s;
}

// ---- W f32 [E,900,512] -> bf16 fragment tiles wt2[e][ncg][kc][col16][kk32] ----
// element (e, n=ncg*16+col, k=kc*32+kk) at ((e*32+ncg)*29+kc)*512 + col*32 + kk
__global__ __launch_bounds__(256) void cvtw2_k(const float* __restrict__ W,
                                               unsigned short* __restrict__ wt2){
  __shared__ unsigned short lds[32][512];
  int t = threadIdx.x;
  int kc = blockIdx.x, e = blockIdx.y;
  for (int kk = 0; kk < 32; ++kk){
    int k = kc*32 + kk;
    if (k < DIN){
      const float* wr = W + ((size_t)e*DIN + k)*DM;
      lds[kk][t]       = f2bf(wr[t]);
      lds[kk][t + 256] = f2bf(wr[t + 256]);
    } else {
      lds[kk][t] = 0; lds[kk][t + 256] = 0;
    }
  }
  __syncthreads();
  int ncg = t >> 3, q = t & 7;
  unsigned short* ob = wt2 + (((size_t)e*32 + ncg)*29 + kc)*512;
  for (int i = 0; i < 8; ++i){
    int fb = i*64 + q*8;          // ushort offset within this frag-tile
    int col = fb >> 5, kk0 = fb & 31;
    ushort8 y;
    #pragma unroll
    for (int j = 0; j < 8; ++j) y[j] = lds[kk0 + j][ncg*16 + col];
    *((ushort8*)(ob + fb)) = y;
  }
}

// ---- gating: thread-per-row; no hot atomics ----
__global__ __launch_bounds__(256) void gating_k(const float* __restrict__ logits,
                                                const int* __restrict__ masks,
                                                int* __restrict__ counts,
                                                float* __restrict__ partials,
                                                int* __restrict__ pidlr,
                                                float2* __restrict__ gatesb,
                                                float* __restrict__ w8,
                                                int* __restrict__ blockbase){
  __shared__ int hist[64];
  __shared__ float wsum[4];
  int t = threadIdx.x;
  if (t < 64) hist[t] = 0;
  __syncthreads();
  int b = blockIdx.x*256 + t;
  float4 l0 = *(const float4*)&logits[(size_t)b*8];
  float4 l1 = *(const float4*)&logits[(size_t)b*8 + 4];
  int4  m0 = *(const int4*)&masks[(size_t)b*8];
  int4  m1 = *(const int4*)&masks[(size_t)b*8 + 4];
  float raw[8] = {l0.x,l0.y,l0.z,l0.w,l1.x,l1.y,l1.z,l1.w};
  int   mk[8]  = {m0.x,m0.y,m0.z,m0.w,m1.x,m1.y,m1.z,m1.w};
  float mx = raw[0];
  for (int e = 1; e < 8; e++) mx = fmaxf(mx, raw[e]);
  float Z = 0.f;
  for (int e = 0; e < 8; e++){ raw[e] = expf(raw[e]-mx); Z += raw[e]; }
  float invZ = 1.f/Z;
  float act[8], ina[8]; float srm = 0.f, isum = 0.f;
  for (int e = 0; e < 8; e++){
    raw[e] *= invZ;
    if (mk[e] == 1){ act[e] = raw[e]; ina[e] = 0.f; srm += raw[e]; }
    else           { act[e] = 0.f;    ina[e] = raw[e]; isum += raw[e]; }
  }
  float v1 = -1.f, v2 = -1.f; int e1 = 0, e2 = 0;
  for (int e = 0; e < 8; e++){
    float a = act[e];
    if (a > v1){ v2 = v1; e2 = e1; v1 = a; e1 = e; }
    else if (a > v2){ v2 = a; e2 = e; }
  }
  float den = v1 + v2 + EPSF;
  float g1 = v1/den, g2 = v2/den;
  int lo, hi; float gl, gh;
  if (e1 < e2){ lo = e1; hi = e2; gl = g1; gh = g2; }
  else        { lo = e2; hi = e1; gl = g2; gh = g1; }
  int pid = lo*8 + hi;
  float invI = 1.f/(isum + EPSF);
  for (int e = 0; e < 8; e++) w8[(size_t)b*8 + e] = ina[e]*invI;
  gatesb[b] = make_float2(gl, gh);
  int lr = atomicAdd(&hist[pid], 1);     // LDS atomic: local rank
  pidlr[b] = pid | (lr << 8);
  // block reduce srm -> partials[blockIdx]
  float s = srm;
  for (int sft = 32; sft > 0; sft >>= 1) s += __shfl_down(s, sft, 64);
  if ((t & 63) == 0) wsum[t >> 6] = s;
  __syncthreads();
  if (t < 64){
    int c = hist[t];
    int base = 0;
    if (c > 0) base = atomicAdd(&counts[t], c);   // <=64 atomics/block
    blockbase[blockIdx.x*64 + t] = base;
  }
  if (t == 0) partials[blockIdx.x] = wsum[0] + wsum[1] + wsum[2] + wsum[3];
}

// ---- selection embedding (+ fused scatter): coalesced, 2 rows per block ----
__global__ __launch_bounds__(256) void selemb_k(const float* __restrict__ sel,
                                                const float* __restrict__ w8,
                                                const int* __restrict__ pidlr,
                                                const int* __restrict__ off,
                                                const int* __restrict__ blockbase,
                                                int* __restrict__ rows_s,
                                                float* __restrict__ out){
  int t = threadIdx.x;
  int b = blockIdx.x*2 + (t >> 7);
  int d = t & 127;
  if (d == 0){
    int pl = pidlr[b];
    int p = pl & 63;
    int lr = pl >> 8;
    rows_s[off[p] + blockbase[(b >> 8)*64 + p] + lr] = b;
  }
  const float* wr = w8 + (size_t)b*8;
  const float* sb = sel + (size_t)b*(8*DSEL);
  float a = 0.f;
  for (int e = 0; e < 8; e++) a += wr[e] * sb[e*DSEL + d];
  out[OUT_SEL + (size_t)b*DSEL + d] = a;
}

// ---- worklist: one 64-lane wave; shuffle scans; guide loss ----
__global__ void worklist_k(const int* __restrict__ counts,
                           const float* __restrict__ partials,
                           int* __restrict__ off, int* __restrict__ ntp,
                           int4* __restrict__ entries,
                           float* __restrict__ out){
  int lane = threadIdx.x;      // 64 threads
  int c = counts[lane];
  int sc = c;
  for (int s = 1; s < 64; s <<= 1){ int v = __shfl_up(sc, s, 64); if (lane >= s) sc += v; }
  int offp = sc - c;
  off[lane] = offp;
  int nt = (c + 127) >> 7;
  int snt = nt;
  for (int s = 1; s < 64; s <<= 1){ int v = __shfl_up(snt, s, 64); if (lane >= s) snt += v; }
  int tbase = snt - nt;
  int elo = lane >> 3, ehi = lane & 7;
  for (int j = 0; j < nt; ++j){
    int nr = c - j*128; if (nr > 128) nr = 128;
    entries[tbase + j] = make_int4(elo, ehi, offp + j*128, nr);
  }
  int tot = __shfl(snt, 63, 64);
  if (lane == 0) *ntp = tot;
  float p = partials[lane];
  for (int s = 32; s > 0; s >>= 1) p += __shfl_down(p, s, 64);
  if (lane == 0){
    float sv = p * (1.f/B_ROWS);
    float d = 1.f - sv;
    out[OUT_GUIDE] = d*d;
  }
}

// ---- grouped GEMM v2b: NO LDS, NO barriers. A from f32 x (row-gather,
//      in-register bf16 pack, pipelined 1 K-step ahead); W from frag-tiled
//      wt2 (contiguous 1KB/wave tiles, pipelined 1 nt ahead). ----

#define LDRAW(kks) { \
  r0 = *(const float4*)(ap0 + (kks)*32); r1 = *(const float4*)(ap0 + (kks)*32 + 4); \
  r2 = *(const float4*)(ap1 + (kks)*32); r3 = *(const float4*)(ap1 + (kks)*32 + 4); \
  r4 = *(const float4*)(ap2 + (kks)*32); r5 = *(const float4*)(ap2 + (kks)*32 + 4); \
  r6 = *(const float4*)(ap3 + (kks)*32); r7 = *(const float4*)(ap3 + (kks)*32 + 4); }

// tail K-step (k 896..899 valid): always-in-bounds loads, value-select zeros
#define LDRAW_TAIL() { \
  float4 z = make_float4(0.f,0.f,0.f,0.f); \
  float4 t0 = *(const float4*)(ap0 - quad*8 + 896); \
  float4 t1 = *(const float4*)(ap1 - quad*8 + 896); \
  float4 t2 = *(const float4*)(ap2 - quad*8 + 896); \
  float4 t3 = *(const float4*)(ap3 - quad*8 + 896); \
  r0 = (quad==0)? t0 : z; r1 = z; \
  r2 = (quad==0)? t1 : z; r3 = z; \
  r4 = (quad==0)? t2 : z; r5 = z; \
  r6 = (quad==0)? t3 : z; r7 = z; }

#define CVT(dst) { \
  dst##0 = pack8(r0, r1); dst##1 = pack8(r2, r3); \
  dst##2 = pack8(r4, r5); dst##3 = pack8(r6, r7); }

#define MF(afX, b, ei, nt) { \
  acc[ei][0][nt] = __builtin_amdgcn_mfma_f32_16x16x32_bf16(afX##0, b, acc[ei][0][nt], 0, 0, 0); \
  acc[ei][1][nt] = __builtin_amdgcn_mfma_f32_16x16x32_bf16(afX##1, b, acc[ei][1][nt], 0, 0, 0); \
  acc[ei][2][nt] = __builtin_amdgcn_mfma_f32_16x16x32_bf16(afX##2, b, acc[ei][2][nt], 0, 0, 0); \
  acc[ei][3][nt] = __builtin_amdgcn_mfma_f32_16x16x32_bf16(afX##3, b, acc[ei][3][nt], 0, 0, 0); }

#define STEP(afX, kks, LASTF) { \
  short8 b0n, b1n; \
  /* nt = 0 */ \
  b0n = *((const short8*)(bp0 + 1*FRSTRIDE + (kks)*512)); \
  b1n = *((const short8*)(bp1 + 1*FRSTRIDE + (kks)*512)); \
  MF(afX, b0c, 0, 0); MF(afX, b1c, 1, 0); b0c = b0n; b1c = b1n; \
  /* nt = 1 */ \
  b0n = *((const short8*)(bp0 + 2*FRSTRIDE + (kks)*512)); \
  b1n = *((const short8*)(bp1 + 2*FRSTRIDE + (kks)*512)); \
  MF(afX, b0c, 0, 1); MF(afX, b1c, 1, 1); b0c = b0n; b1c = b1n; \
  /* nt = 2 */ \
  b0n = *((const short8*)(bp0 + 3*FRSTRIDE + (kks)*512)); \
  b1n = *((const short8*)(bp1 + 3*FRSTRIDE + (kks)*512)); \
  MF(afX, b0c, 0, 2); MF(afX, b1c, 1, 2); b0c = b0n; b1c = b1n; \
  /* nt = 3; cross-prefetch next K-step's nt=0 */ \
  if (!(LASTF)){ \
    b0n = *((const short8*)(bp0 + ((kks)+1)*512)); \
    b1n = *((const short8*)(bp1 + ((kks)+1)*512)); \
  } \
  MF(afX, b0c, 0, 3); MF(afX, b1c, 1, 3); b0c = b0n; b1c = b1n; }

__global__ __launch_bounds__(256, 2) void gemm_k(const float* __restrict__ xf,
                                                 const unsigned short* __restrict__ wt2,
                                                 const float* __restrict__ bias,
                                                 const int* __restrict__ ntp,
                                                 const int4* __restrict__ entries,
                                                 const int* __restrict__ rows_s,
                                                 const float2* __restrict__ gatesb,
                                                 float* __restrict__ out){
  int tile = blockIdx.x;
  if (tile >= *ntp) return;
  int4 ent = entries[tile];
  int elo = ent.x, ehi = ent.y, start = ent.z, nrows = ent.w;

  int t = threadIdx.x, lane = t & 63, wid = t >> 6;
  int wrow = wid >> 1, wcol = wid & 1;
  int quad = lane >> 4, l16 = lane & 15;
  int ncg0 = blockIdx.y*8 + wcol*4;     // this wave's first 16-col group

  // per-lane A row pointers (row-gather; invalid rows -> row 0, masked at store)
  const float* ap0; const float* ap1; const float* ap2; const float* ap3;
  {
    int rr, g;
    rr = wrow*64 + 0*16 + l16; g = (rr < nrows) ? rows_s[start + rr] : 0;
    ap0 = xf + (size_t)g*DIN + quad*8;
    rr = wrow*64 + 1*16 + l16; g = (rr < nrows) ? rows_s[start + rr] : 0;
    ap1 = xf + (size_t)g*DIN + quad*8;
    rr = wrow*64 + 2*16 + l16; g = (rr < nrows) ? rows_s[start + rr] : 0;
    ap2 = xf + (size_t)g*DIN + quad*8;
    rr = wrow*64 + 3*16 + l16; g = (rr < nrows) ? rows_s[start + rr] : 0;
    ap3 = xf + (size_t)g*DIN + quad*8;
  }
  const unsigned short* bp0 = wt2 + ((size_t)(elo*32 + ncg0)*29)*512 + l16*32 + quad*8;
  const unsigned short* bp1 = wt2 + ((size_t)(ehi*32 + ncg0)*29)*512 + l16*32 + quad*8;

  floatx4 acc[2][4][4];
  #pragma unroll
  for (int i = 0; i < 2; i++)
    #pragma unroll
    for (int j = 0; j < 4; j++)
      #pragma unroll
      for (int k = 0; k < 4; k++)
        #pragma unroll
        for (int r = 0; r < 4; r++) acc[i][j][k][r] = 0.f;

  float4 r0,r1,r2,r3,r4,r5,r6,r7;
  short8 afA0, afA1, afA2, afA3;
  short8 afB0, afB1, afB2, afB3;

  LDRAW(0);
  CVT(afA);
  short8 b0c = *((const short8*)(bp0));
  short8 b1c = *((const short8*)(bp1));

  for (int ks = 0; ks < 28; ks += 2){
    LDRAW(ks+1);                 // in flight under STEP(afA)
    STEP(afA, ks, false);
    CVT(afB);
    if (ks + 2 < 28){ LDRAW(ks+2); } else { LDRAW_TAIL(); }
    STEP(afB, ks+1, false);
    CVT(afA);
  }
  STEP(afA, 28, true);

  // epilogue: gates + bias in f32 (== ref's g*(xW+b) summed over top-2)
  float blo[4], bhi[4];
  #pragma unroll
  for (int nt = 0; nt < 4; ++nt){
    int n = (ncg0 + nt)*16 + l16;
    blo[nt] = bias[elo*DM + n];
    bhi[nt] = bias[ehi*DM + n];
  }
  #pragma unroll
  for (int mt = 0; mt < 4; ++mt){
    #pragma unroll
    for (int r = 0; r < 4; ++r){
      int rr = wrow*64 + mt*16 + quad*4 + r;
      if (rr < nrows){
        int grow = rows_s[start + rr];
        float2 gg = gatesb[grow];
        float* orow = out + (size_t)grow*DM;
        #pragma unroll
        for (int nt = 0; nt < 4; ++nt){
          int n = (ncg0 + nt)*16 + l16;
          float v = gg.x*(acc[0][mt][nt][r] + blo[nt]) + gg.y*(acc[1][mt][nt][r] + bhi[nt]);
          orow[n] = bf2f(f2bf(v));
        }
      }
    }
  }
}

extern "C" void kernel_launch(void* const* d_in, const int* in_sizes, int n_in,
                              void* d_out, int out_size, void* d_ws, size_t ws_size,
                              hipStream_t stream){
  const float* x      = (const float*)d_in[0];
  const float* logits = (const float*)d_in[1];
  const int*   masks  = (const int*)d_in[2];
  const float* sel    = (const float*)d_in[3];
  const float* W      = (const float*)d_in[4];
  const float* bias   = (const float*)d_in[5];
  float* out = (float*)d_out;
  char* ws = (char*)d_ws;
  int*    counts   = (int*)(ws + WS_COUNTS);
  float*  partials = (float*)(ws + WS_PART);
  int*    ntp      = (int*)(ws + WS_NT);
  int*    off      = (int*)(ws + WS_OFF);
  int4*   entries  = (int4*)(ws + WS_ENT);
  int*    blockbase= (int*)(ws + WS_BB);
  int*    pidlr    = (int*)(ws + WS_PIDLR);
  float2* gatesb   = (float2*)(ws + WS_GATEB);
  float*  w8       = (float*)(ws + WS_W8);
  int*    rows_s   = (int*)(ws + WS_ROWSS);
  unsigned short* wt2 = (unsigned short*)(ws + WS_WT);

  hipMemsetAsync(ws, 0, 256, stream);   // counts
  cvtw2_k<<<dim3(29, 8), 256, 0, stream>>>(W, wt2);
  gating_k<<<B_ROWS/256, 256, 0, stream>>>(logits, masks, counts, partials, pidlr, gatesb, w8, blockbase);
  worklist_k<<<1, 64, 0, stream>>>(counts, partials, off, ntp, entries, out);
  selemb_k<<<B_ROWS/2, 256, 0, stream>>>(sel, w8, pidlr, off, blockbase, rows_s, out);
  gemm_k<<<dim3(MAXT, 4), 256, 0, stream>>>(x, wt2, bias, ntp, entries, rows_s, gatesb, out);
}

// Round 4
// 286.215 us; speedup vs baseline: 1.1894x; 1.1622x over previous
//
#include <hip/hip_runtime.h>
#include <hip/hip_bf16.h>

// f32-uniform output buffer: final_out [B,512] (bf16-rounded f32),
// guide_loss f32 @ B*512, sel_emb [B,128] f32 @ B*512+1.
// B=16384, E=8, D_IN=900, D_MODEL=512, D_SEL=128, top-2.

#define B_ROWS 16384
#define DIN 900
#define DM 512
#define DSEL 128
#define KP 928
#define NKS 29
#define MAXT 192
#define EPSF 1e-9f

#define OUT_GUIDE (B_ROWS*DM)
#define OUT_SEL   (B_ROWS*DM + 1)

// workspace layout (bytes); total ~8.4 MB (proven footprint)
#define WS_COUNTS 0                      // int[64]
#define WS_PART   512                    // float[64]
#define WS_NT     768                    // int
#define WS_OFF    1024                   // int[64]
#define WS_ENT    2048                   // int4[448]
#define WS_BB     9216                   // int[64*64] block bases
#define WS_PIDLR  25600                  // int[B]  pid | (lrank<<8)
#define WS_GATEB  91136                  // float2[B]
#define WS_W8     222208                 // float[B*8] inactive-mixture weights
#define WS_ROWSS  746496                 // int[B]
#define WS_WT     812032                 // ushort[E*32*29*512] frag-tiled W (7.6 MB)

typedef __attribute__((ext_vector_type(8))) short short8;
typedef __attribute__((ext_vector_type(8))) unsigned short ushort8;
typedef __attribute__((ext_vector_type(4))) float floatx4;

__device__ inline unsigned short f2bf(float v){
  union { __hip_bfloat16 h; unsigned short u; } c;
  c.h = __float2bfloat16(v);
  return c.u;
}
__device__ inline float bf2f(unsigned short u){
  union { unsigned int i; float f; } c;
  c.i = ((unsigned int)u) << 16;
  return c.f;
}
__device__ inline ushort8 pack8u(float4 a, float4 b){
  ushort8 c;
  c[0]=f2bf(a.x); c[1]=f2bf(a.y); c[2]=f2bf(a.z); c[3]=f2bf(a.w);
  c[4]=f2bf(b.x); c[5]=f2bf(b.y); c[6]=f2bf(b.z); c[7]=f2bf(b.w);
  return c;
}

// ---- W f32 [E,900,512] -> bf16 fragment tiles wt2[e][ncg][kc][col16][kk32] ----
// element (e, n=ncg*16+col, k=kc*32+kk) at ((e*32+ncg)*29+kc)*512 + col*32 + kk
__global__ __launch_bounds__(256) void cvtw2_k(const float* __restrict__ W,
                                               unsigned short* __restrict__ wt2){
  __shared__ unsigned short lds[32][512];
  int t = threadIdx.x;
  int kc = blockIdx.x, e = blockIdx.y;
  for (int kk = 0; kk < 32; ++kk){
    int k = kc*32 + kk;
    if (k < DIN){
      const float* wr = W + ((size_t)e*DIN + k)*DM;
      lds[kk][t]       = f2bf(wr[t]);
      lds[kk][t + 256] = f2bf(wr[t + 256]);
    } else {
      lds[kk][t] = 0; lds[kk][t + 256] = 0;
    }
  }
  __syncthreads();
  int ncg = t >> 3, q = t & 7;
  unsigned short* ob = wt2 + (((size_t)e*32 + ncg)*29 + kc)*512;
  for (int i = 0; i < 8; ++i){
    int fb = i*64 + q*8;          // ushort offset within this frag-tile
    int col = fb >> 5, kk0 = fb & 31;
    ushort8 y;
    #pragma unroll
    for (int j = 0; j < 8; ++j) y[j] = lds[kk0 + j][ncg*16 + col];
    *((ushort8*)(ob + fb)) = y;
  }
}

// ---- gating: thread-per-row; no hot atomics ----
__global__ __launch_bounds__(256) void gating_k(const float* __restrict__ logits,
                                                const int* __restrict__ masks,
                                                int* __restrict__ counts,
                                                float* __restrict__ partials,
                                                int* __restrict__ pidlr,
                                                float2* __restrict__ gatesb,
                                                float* __restrict__ w8,
                                                int* __restrict__ blockbase){
  __shared__ int hist[64];
  __shared__ float wsum[4];
  int t = threadIdx.x;
  if (t < 64) hist[t] = 0;
  __syncthreads();
  int b = blockIdx.x*256 + t;
  float4 l0 = *(const float4*)&logits[(size_t)b*8];
  float4 l1 = *(const float4*)&logits[(size_t)b*8 + 4];
  int4  m0 = *(const int4*)&masks[(size_t)b*8];
  int4  m1 = *(const int4*)&masks[(size_t)b*8 + 4];
  float raw[8] = {l0.x,l0.y,l0.z,l0.w,l1.x,l1.y,l1.z,l1.w};
  int   mk[8]  = {m0.x,m0.y,m0.z,m0.w,m1.x,m1.y,m1.z,m1.w};
  float mx = raw[0];
  for (int e = 1; e < 8; e++) mx = fmaxf(mx, raw[e]);
  float Z = 0.f;
  for (int e = 0; e < 8; e++){ raw[e] = expf(raw[e]-mx); Z += raw[e]; }
  float invZ = 1.f/Z;
  float act[8], ina[8]; float srm = 0.f, isum = 0.f;
  for (int e = 0; e < 8; e++){
    raw[e] *= invZ;
    if (mk[e] == 1){ act[e] = raw[e]; ina[e] = 0.f; srm += raw[e]; }
    else           { act[e] = 0.f;    ina[e] = raw[e]; isum += raw[e]; }
  }
  float v1 = -1.f, v2 = -1.f; int e1 = 0, e2 = 0;
  for (int e = 0; e < 8; e++){
    float a = act[e];
    if (a > v1){ v2 = v1; e2 = e1; v1 = a; e1 = e; }
    else if (a > v2){ v2 = a; e2 = e; }
  }
  float den = v1 + v2 + EPSF;
  float g1 = v1/den, g2 = v2/den;
  int lo, hi; float gl, gh;
  if (e1 < e2){ lo = e1; hi = e2; gl = g1; gh = g2; }
  else        { lo = e2; hi = e1; gl = g2; gh = g1; }
  int pid = lo*8 + hi;
  float invI = 1.f/(isum + EPSF);
  for (int e = 0; e < 8; e++) w8[(size_t)b*8 + e] = ina[e]*invI;
  gatesb[b] = make_float2(gl, gh);
  int lr = atomicAdd(&hist[pid], 1);     // LDS atomic: local rank
  pidlr[b] = pid | (lr << 8);
  // block reduce srm -> partials[blockIdx]
  float s = srm;
  for (int sft = 32; sft > 0; sft >>= 1) s += __shfl_down(s, sft, 64);
  if ((t & 63) == 0) wsum[t >> 6] = s;
  __syncthreads();
  if (t < 64){
    int c = hist[t];
    int base = 0;
    if (c > 0) base = atomicAdd(&counts[t], c);   // <=64 atomics/block
    blockbase[blockIdx.x*64 + t] = base;
  }
  if (t == 0) partials[blockIdx.x] = wsum[0] + wsum[1] + wsum[2] + wsum[3];
}

// ---- selection embedding (+ fused scatter): coalesced, 2 rows per block ----
__global__ __launch_bounds__(256) void selemb_k(const float* __restrict__ sel,
                                                const float* __restrict__ w8,
                                                const int* __restrict__ pidlr,
                                                const int* __restrict__ off,
                                                const int* __restrict__ blockbase,
                                                int* __restrict__ rows_s,
                                                float* __restrict__ out){
  int t = threadIdx.x;
  int b = blockIdx.x*2 + (t >> 7);
  int d = t & 127;
  if (d == 0){
    int pl = pidlr[b];
    int p = pl & 63;
    int lr = pl >> 8;
    rows_s[off[p] + blockbase[(b >> 8)*64 + p] + lr] = b;
  }
  const float* wr = w8 + (size_t)b*8;
  const float* sb = sel + (size_t)b*(8*DSEL);
  float a = 0.f;
  for (int e = 0; e < 8; e++) a += wr[e] * sb[e*DSEL + d];
  out[OUT_SEL + (size_t)b*DSEL + d] = a;
}

// ---- worklist: one 64-lane wave; shuffle scans; guide loss ----
__global__ void worklist_k(const int* __restrict__ counts,
                           const float* __restrict__ partials,
                           int* __restrict__ off, int* __restrict__ ntp,
                           int4* __restrict__ entries,
                           float* __restrict__ out){
  int lane = threadIdx.x;      // 64 threads
  int c = counts[lane];
  int sc = c;
  for (int s = 1; s < 64; s <<= 1){ int v = __shfl_up(sc, s, 64); if (lane >= s) sc += v; }
  int offp = sc - c;
  off[lane] = offp;
  int nt = (c + 127) >> 7;
  int snt = nt;
  for (int s = 1; s < 64; s <<= 1){ int v = __shfl_up(snt, s, 64); if (lane >= s) snt += v; }
  int tbase = snt - nt;
  int elo = lane >> 3, ehi = lane & 7;
  for (int j = 0; j < nt; ++j){
    int nr = c - j*128; if (nr > 128) nr = 128;
    entries[tbase + j] = make_int4(elo, ehi, offp + j*128, nr);
  }
  int tot = __shfl(snt, 63, 64);
  if (lane == 0) *ntp = tot;
  float p = partials[lane];
  for (int s = 32; s > 0; s >>= 1) p += __shfl_down(p, s, 64);
  if (lane == 0){
    float sv = p * (1.f/B_ROWS);
    float d = 1.f - sv;
    out[OUT_GUIDE] = d*d;
  }
}

// ---- grouped GEMM v3: A AND B staged in LDS (multicast to all 4 waves),
//      padded 80B row stride (conflict-free b128 reads), double-buffered,
//      ONE barrier per K-step, next-step globals issued before MFMAs. ----
// Cache-level traffic ~550 MB vs v2's ~1 TB (theory: LLC-BW-bound).

#define ALOAD(kk) { \
  if ((kk) < 28){ \
    const float4* p = (const float4*)(xrow + (kk)*32); \
    a0 = p[0]; a1 = p[1]; a2 = p[2]; a3 = p[3]; \
  } else { \
    float tmp[16]; \
    _Pragma("unroll") \
    for (int j = 0; j < 16; ++j){ \
      int k = (kk)*32 + skc*16 + j; \
      tmp[j] = (k < DIN) ? xrow[(kk)*32 + j] : 0.f; \
    } \
    a0 = make_float4(tmp[0],tmp[1],tmp[2],tmp[3]); \
    a1 = make_float4(tmp[4],tmp[5],tmp[6],tmp[7]); \
    a2 = make_float4(tmp[8],tmp[9],tmp[10],tmp[11]); \
    a3 = make_float4(tmp[12],tmp[13],tmp[14],tmp[15]); \
  } }

#define BLOAD(kk) { \
  bw0 = *((const ushort8*)(bg0 + (size_t)(kk)*512)); \
  bw1 = *((const ushort8*)(bg1 + (size_t)(kk)*512)); \
  bw2 = *((const ushort8*)(bg2 + (size_t)(kk)*512)); \
  bw3 = *((const ushort8*)(bg3 + (size_t)(kk)*512)); }

#define AWRITE(buf) { \
  *((ushort8*)&as_[buf][srow*40 + skc*16])     = pack8u(a0, a1); \
  *((ushort8*)&as_[buf][srow*40 + skc*16 + 8]) = pack8u(a2, a3); }

#define BWRITE(buf) { \
  *((ushort8*)&bs_[buf][bl0]) = bw0; \
  *((ushort8*)&bs_[buf][bl1]) = bw1; \
  *((ushort8*)&bs_[buf][bl2]) = bw2; \
  *((ushort8*)&bs_[buf][bl3]) = bw3; }

__global__ __launch_bounds__(256, 2) void gemm_k(const float* __restrict__ xf,
                                                 const unsigned short* __restrict__ wt2,
                                                 const float* __restrict__ bias,
                                                 const int* __restrict__ ntp,
                                                 const int4* __restrict__ entries,
                                                 const int* __restrict__ rows_s,
                                                 const float2* __restrict__ gatesb,
                                                 float* __restrict__ out){
  int tile = blockIdx.x;
  if (tile >= *ntp) return;
  int4 ent = entries[tile];
  int elo = ent.x, ehi = ent.y, start = ent.z, nrows = ent.w;

  __shared__ __align__(16) unsigned short as_[2][128*40];   // A bf16, 80B rows
  __shared__ __align__(16) unsigned short bs_[2][16*16*40]; // B frag, 80B cols
  __shared__ int   gidx_s[128];
  __shared__ float glo_s[128];
  __shared__ float ghi_s[128];

  int t = threadIdx.x;
  if (t < 128){
    if (t < nrows){
      int g = rows_s[start + t];
      gidx_s[t] = g;
      float2 gg = gatesb[g];
      glo_s[t] = gg.x; ghi_s[t] = gg.y;
    } else { gidx_s[t] = -1; glo_s[t] = 0.f; ghi_s[t] = 0.f; }
  }
  __syncthreads();

  int lane = t & 63, wid = t >> 6;
  int wrow = wid >> 1, wcol = wid & 1;
  int quad = lane >> 4, l16 = lane & 15;

  // A staging mapping: thread t stages row t>>1, half (t&1)*16 of each 32-k chunk
  int srow = t >> 1, skc = t & 1;
  int sg = gidx_s[srow];
  const float* xrow = xf + (size_t)(sg >= 0 ? sg : 0)*DIN + skc*16;

  // B staging mapping: unit u = i*256 + t over 1024 16B-units per K-step
  //   e = u>>9, j = (u>>6)&7 (local ncg), col = (t&63)>>2, q = t&3
  int bcol = (t & 63) >> 2, bq = t & 3;
  const unsigned short* bg0; const unsigned short* bg1;
  const unsigned short* bg2; const unsigned short* bg3;
  int bl0, bl1, bl2, bl3;
  {
    int u0 = t, u1 = 256 + t, u2 = 512 + t, u3 = 768 + t;
    int j0 = (u0 >> 6) & 7, j1 = (u1 >> 6) & 7, j2 = (u2 >> 6) & 7, j3 = (u3 >> 6) & 7;
    int goff = (t & 63)*8;   // unit offset in shorts within frag tile
    bg0 = wt2 + ((size_t)(elo*32 + blockIdx.y*8 + j0)*29)*512 + goff;
    bg1 = wt2 + ((size_t)(elo*32 + blockIdx.y*8 + j1)*29)*512 + goff;
    bg2 = wt2 + ((size_t)(ehi*32 + blockIdx.y*8 + j2)*29)*512 + goff;
    bg3 = wt2 + ((size_t)(ehi*32 + blockIdx.y*8 + j3)*29)*512 + goff;
    bl0 = ((0*8 + j0)*16 + bcol)*40 + bq*8;
    bl1 = ((0*8 + j1)*16 + bcol)*40 + bq*8;
    bl2 = ((1*8 + j2)*16 + bcol)*40 + bq*8;
    bl3 = ((1*8 + j3)*16 + bcol)*40 + bq*8;
  }

  floatx4 acc[2][4][4];
  #pragma unroll
  for (int i = 0; i < 2; i++)
    #pragma unroll
    for (int j = 0; j < 4; j++)
      #pragma unroll
      for (int k = 0; k < 4; k++)
        #pragma unroll
        for (int r = 0; r < 4; r++) acc[i][j][k][r] = 0.f;

  float4 a0, a1, a2, a3;
  ushort8 bw0, bw1, bw2, bw3;

  // prologue: stage K-step 0 into buffer 0
  ALOAD(0); BLOAD(0);
  AWRITE(0); BWRITE(0);
  __syncthreads();

  for (int ks = 0; ks < NKS; ++ks){
    int cur = ks & 1;
    int nk = ks + 1;
    if (nk < NKS){ ALOAD(nk); BLOAD(nk); }   // in flight under MFMAs

    short8 af[4];
    #pragma unroll
    for (int mt = 0; mt < 4; ++mt)
      af[mt] = *((const short8*)&as_[cur][(wrow*64 + mt*16 + l16)*40 + quad*8]);
    #pragma unroll
    for (int e = 0; e < 2; ++e){
      #pragma unroll
      for (int nt = 0; nt < 4; ++nt){
        short8 bfr = *((const short8*)&bs_[cur][((e*8 + wcol*4 + nt)*16 + l16)*40 + quad*8]);
        #pragma unroll
        for (int mt = 0; mt < 4; ++mt)
          acc[e][mt][nt] = __builtin_amdgcn_mfma_f32_16x16x32_bf16(af[mt], bfr, acc[e][mt][nt], 0, 0, 0);
      }
    }

    if (nk < NKS){ AWRITE(cur ^ 1); BWRITE(cur ^ 1); }
    __syncthreads();
  }

  // epilogue: gates + bias in f32 (== ref's g*(xW+b) summed over top-2)
  int colbase = blockIdx.y*128 + wcol*64;
  float blo[4], bhi[4];
  #pragma unroll
  for (int nt = 0; nt < 4; ++nt){
    int n = colbase + nt*16 + l16;
    blo[nt] = bias[elo*DM + n];
    bhi[nt] = bias[ehi*DM + n];
  }
  #pragma unroll
  for (int mt = 0; mt < 4; ++mt){
    #pragma unroll
    for (int r = 0; r < 4; ++r){
      int rr = wrow*64 + mt*16 + quad*4 + r;
      int grow = gidx_s[rr];
      if (grow >= 0){
        float2 gg = gatesb[grow];
        float* orow = out + (size_t)grow*DM;
        #pragma unroll
        for (int nt = 0; nt < 4; ++nt){
          int n = colbase + nt*16 + l16;
          float v = gg.x*(acc[0][mt][nt][r] + blo[nt]) + gg.y*(acc[1][mt][nt][r] + bhi[nt]);
          orow[n] = bf2f(f2bf(v));
        }
      }
    }
  }
}

extern "C" void kernel_launch(void* const* d_in, const int* in_sizes, int n_in,
                              void* d_out, int out_size, void* d_ws, size_t ws_size,
                              hipStream_t stream){
  const float* x      = (const float*)d_in[0];
  const float* logits = (const float*)d_in[1];
  const int*   masks  = (const int*)d_in[2];
  const float* sel    = (const float*)d_in[3];
  const float* W      = (const float*)d_in[4];
  const float* bias   = (const float*)d_in[5];
  float* out = (float*)d_out;
  char* ws = (char*)d_ws;
  int*    counts   = (int*)(ws + WS_COUNTS);
  float*  partials = (float*)(ws + WS_PART);
  int*    ntp      = (int*)(ws + WS_NT);
  int*    off      = (int*)(ws + WS_OFF);
  int4*   entries  = (int4*)(ws + WS_ENT);
  int*    blockbase= (int*)(ws + WS_BB);
  int*    pidlr    = (int*)(ws + WS_PIDLR);
  float2* gatesb   = (float2*)(ws + WS_GATEB);
  float*  w8       = (float*)(ws + WS_W8);
  int*    rows_s   = (int*)(ws + WS_ROWSS);
  unsigned short* wt2 = (unsigned short*)(ws + WS_WT);

  hipMemsetAsync(ws, 0, 256, stream);   // counts
  cvtw2_k<<<dim3(29, 8), 256, 0, stream>>>(W, wt2);
  gating_k<<<B_ROWS/256, 256, 0, stream>>>(logits, masks, counts, partials, pidlr, gatesb, w8, blockbase);
  worklist_k<<<1, 64, 0, stream>>>(counts, partials, off, ntp, entries, out);
  selemb_k<<<B_ROWS/2, 256, 0, stream>>>(sel, w8, pidlr, off, blockbase, rows_s, out);
  gemm_k<<<dim3(MAXT, 4), 256, 0, stream>>>(x, wt2, bias, ntp, entries, rows_s, gatesb, out);
}